// Round 1
// baseline (133.731 us; speedup 1.0000x reference)
//
#include <hip/hip_runtime.h>

#define BATCH 16
#define HH 512
#define WW 512
#define PLANE (HH*WW)

// ---------------- K1: guide (channel mean) + 15x15 replicate min-pool ----------------
#define T1 64
#define HALO 7
#define LW (T1 + 2*HALO)   // 78

__global__ __launch_bounds__(256) void k1_guide_minpool(
    const float* __restrict__ smoky, float* __restrict__ guide, float* __restrict__ p)
{
    __shared__ float dcp[LW*LW];     // per-pixel channel min, with replicate halo
    __shared__ float vmn[T1*LW];     // vertical 15-min
    int nwg = gridDim.x;             // 1024, divisible by 8
    int wg = (blockIdx.x & 7) * (nwg >> 3) + (blockIdx.x >> 3);  // XCD-chunked swizzle
    int img  = wg >> 6;              // 64 tiles per image
    int tile = wg & 63;
    int y0 = (tile >> 3) * T1;
    int x0 = (tile & 7) * T1;
    int t = threadIdx.x;
    const float* s0 = smoky + (size_t)img * 3 * PLANE;
    float* gpl = guide + (size_t)img * PLANE;
    float* ppl = p     + (size_t)img * PLANE;

    for (int i = t; i < LW*LW; i += 256) {
        int ly = i / LW, lx = i - ly * LW;
        int iy = y0 - HALO + ly, ix = x0 - HALO + lx;
        int cy = min(max(iy, 0), HH-1);
        int cx = min(max(ix, 0), WW-1);
        const float* bp = s0 + cy * WW + cx;
        float c0 = bp[0], c1 = bp[PLANE], c2 = bp[2*PLANE];
        dcp[i] = fminf(fminf(c0, c1), c2);
        if (ly >= HALO && ly < HALO+T1 && lx >= HALO && lx < HALO+T1)
            gpl[iy * WW + ix] = (c0 + c1 + c2) * (1.0f/3.0f);
    }
    __syncthreads();
    for (int i = t; i < T1*LW; i += 256) {
        int r = i / LW, c = i - r * LW;
        float m = dcp[r*LW + c];
        #pragma unroll
        for (int d = 1; d < 15; ++d) m = fminf(m, dcp[(r+d)*LW + c]);
        vmn[i] = m;
    }
    __syncthreads();
    for (int i = t; i < T1*T1; i += 256) {
        int r = i >> 6, c = i & 63;
        float m = vmn[r*LW + c];
        #pragma unroll
        for (int d = 1; d < 15; ++d) m = fminf(m, vmn[r*LW + c + d]);
        ppl[(y0+r)*WW + x0 + c] = m;
    }
}

// ---------------- K2: fused 4x box-sum (I, I^2, p, I*p) -> a, b ----------------
#define RS 16
#define NK 526     // 512 + 14 halo columns

__global__ __launch_bounds__(256) void k2_ab(
    const float* __restrict__ guide, const float* __restrict__ p,
    float* __restrict__ a, float* __restrict__ b)
{
    __shared__ float lsI [NK+2];
    __shared__ float lsII[NK+2];
    __shared__ float lsP [NK+2];
    __shared__ float lsIp[NK+2];
    int nwg = gridDim.x;             // 512, divisible by 8
    int wg = (blockIdx.x & 7) * (nwg >> 3) + (blockIdx.x >> 3);
    int img = wg >> 5;               // 32 strips per image
    int y0  = (wg & 31) * RS;
    int t = threadIdx.x;
    const float* gP = guide + (size_t)img * PLANE;
    const float* pP = p     + (size_t)img * PLANE;
    float* aP = a + (size_t)img * PLANE;
    float* bP = b + (size_t)img * PLANE;

    // LDS slot k <-> global column k-7 (zero outside image)
    int g0 = t - 7;            // slot t
    int g1 = t + 249;          // slot t+256
    int g2 = t + 505;          // slot t+512 (threads 0..13)
    bool v0 = (g0 >= 0);
    bool v1 = (g1 < WW);
    bool v2 = (t < 14) && (g2 < WW);

    float sI0=0,sII0=0,sp0=0,sIp0=0;
    float sI1=0,sII1=0,sp1=0,sIp1=0;
    float sI2=0,sII2=0,sp2=0,sIp2=0;

    auto acc = [&](int y, float sgn) {
        if ((unsigned)y >= (unsigned)HH) return;
        const float* gr = gP + y*WW;
        const float* pr = pP + y*WW;
        if (v0) { float g = gr[g0], pv = pr[g0];
            sI0 += sgn*g; sII0 += sgn*g*g; sp0 += sgn*pv; sIp0 += sgn*g*pv; }
        if (v1) { float g = gr[g1], pv = pr[g1];
            sI1 += sgn*g; sII1 += sgn*g*g; sp1 += sgn*pv; sIp1 += sgn*g*pv; }
        if (v2) { float g = gr[g2], pv = pr[g2];
            sI2 += sgn*g; sII2 += sgn*g*g; sp2 += sgn*pv; sIp2 += sgn*g*pv; }
    };

    for (int r = y0 - 7; r < y0 + 7; ++r) acc(r, 1.0f);

    const float inv225 = 1.0f / 225.0f;
    for (int y = y0; y < y0 + RS; ++y) {
        acc(y + 7, 1.0f);
        lsI [t] = sI0;  lsII[t] = sII0;  lsP[t] = sp0;  lsIp[t] = sIp0;
        lsI [t+256] = sI1; lsII[t+256] = sII1; lsP[t+256] = sp1; lsIp[t+256] = sIp1;
        if (t < 14) { lsI[t+512]=sI2; lsII[t+512]=sII2; lsP[t+512]=sp2; lsIp[t+512]=sIp2; }
        __syncthreads();
        int j0 = 2*t;
        float SI = lsI[j0], SII = lsII[j0], SP = lsP[j0], SIp = lsIp[j0];
        #pragma unroll
        for (int d = 1; d < 15; ++d) {
            SI += lsI[j0+d]; SII += lsII[j0+d]; SP += lsP[j0+d]; SIp += lsIp[j0+d];
        }
        float mI = SI*inv225, mP = SP*inv225;
        float cov = SIp*inv225 - mI*mP;
        float var = SII*inv225 - mI*mI;
        float a0 = cov / (var + 1e-3f);
        float b0 = mP - a0*mI;
        // incremental second column
        float SIb  = SI  - lsI [j0] + lsI [j0+15];
        float SIIb = SII - lsII[j0] + lsII[j0+15];
        float SPb  = SP  - lsP [j0] + lsP [j0+15];
        float SIpb = SIp - lsIp[j0] + lsIp[j0+15];
        float mI1 = SIb*inv225, mP1 = SPb*inv225;
        float cov1 = SIpb*inv225 - mI1*mP1;
        float var1 = SIIb*inv225 - mI1*mI1;
        float a1 = cov1 / (var1 + 1e-3f);
        float b1 = mP1 - a1*mI1;
        size_t off = (size_t)y*WW + j0;
        *reinterpret_cast<float2*>(aP + off) = make_float2(a0, a1);
        *reinterpret_cast<float2*>(bP + off) = make_float2(b0, b1);
        __syncthreads();
        acc(y - 7, -1.0f);
    }
}

// ---------------- K3: box-sum of a,b + guided output + final combine ----------------
__global__ __launch_bounds__(256) void k3_final(
    const float* __restrict__ a, const float* __restrict__ b,
    const float* __restrict__ guide, const float* __restrict__ smoky,
    const float* __restrict__ rho, float* __restrict__ out)
{
    __shared__ float lsa[NK+2];
    __shared__ float lsb[NK+2];
    int nwg = gridDim.x;             // 512
    int wg = (blockIdx.x & 7) * (nwg >> 3) + (blockIdx.x >> 3);
    int img = wg >> 5;
    int y0  = (wg & 31) * RS;
    int t = threadIdx.x;
    const float* aP = a + (size_t)img * PLANE;
    const float* bP = b + (size_t)img * PLANE;
    const float* gP = guide + (size_t)img * PLANE;
    const float* sP = smoky + (size_t)img * 3 * PLANE;
    const float* rP = rho   + (size_t)img * 3 * PLANE;
    float* oP = out + (size_t)img * 3 * PLANE;

    int g0 = t - 7, g1 = t + 249, g2 = t + 505;
    bool v0 = (g0 >= 0), v1 = (g1 < WW), v2 = (t < 14) && (g2 < WW);
    float sa0=0, sb0=0, sa1=0, sb1=0, sa2=0, sb2=0;

    auto acc = [&](int y, float sgn) {
        if ((unsigned)y >= (unsigned)HH) return;
        const float* ar = aP + y*WW;
        const float* br = bP + y*WW;
        if (v0) { sa0 += sgn*ar[g0]; sb0 += sgn*br[g0]; }
        if (v1) { sa1 += sgn*ar[g1]; sb1 += sgn*br[g1]; }
        if (v2) { sa2 += sgn*ar[g2]; sb2 += sgn*br[g2]; }
    };
    for (int r = y0 - 7; r < y0 + 7; ++r) acc(r, 1.0f);

    const float inv225 = 1.0f/225.0f;
    const float inv11 = 1.0f/1.1f;
    for (int y = y0; y < y0 + RS; ++y) {
        acc(y + 7, 1.0f);
        lsa[t] = sa0;       lsb[t] = sb0;
        lsa[t+256] = sa1;   lsb[t+256] = sb1;
        if (t < 14) { lsa[t+512] = sa2; lsb[t+512] = sb2; }
        __syncthreads();
        int j0 = 2*t;
        float SA = lsa[j0], SB = lsb[j0];
        #pragma unroll
        for (int d = 1; d < 15; ++d) { SA += lsa[j0+d]; SB += lsb[j0+d]; }
        float SA1 = SA - lsa[j0] + lsa[j0+15];
        float SB1 = SB - lsb[j0] + lsb[j0+15];
        size_t off = (size_t)y*WW + j0;
        float2 gv = *reinterpret_cast<const float2*>(gP + off);
        float dcr0 = SA*inv225*gv.x + SB*inv225;
        float dcr1 = SA1*inv225*gv.y + SB1*inv225;
        float f0 = (0.1f + dcr0) * inv11;
        float f1 = (0.1f + dcr1) * inv11;
        #pragma unroll
        for (int c = 0; c < 3; ++c) {
            size_t o2 = (size_t)c*PLANE + off;
            float2 sm = *reinterpret_cast<const float2*>(sP + o2);
            float2 rh = *reinterpret_cast<const float2*>(rP + o2);
            float2 ov;
            ov.x = sm.x - f0*(1.0f - rh.x);
            ov.y = sm.y - f1*(1.0f - rh.y);
            *reinterpret_cast<float2*>(oP + o2) = ov;
        }
        __syncthreads();
        acc(y - 7, -1.0f);
    }
}

extern "C" void kernel_launch(void* const* d_in, const int* in_sizes, int n_in,
                              void* d_out, int out_size, void* d_ws, size_t ws_size,
                              hipStream_t stream) {
    const float* smoky = (const float*)d_in[0];
    const float* rho   = (const float*)d_in[1];
    float* out = (float*)d_out;
    float* ws  = (float*)d_ws;
    const size_t P = (size_t)BATCH * PLANE;   // 4,194,304 floats per plane-set
    float* guide = ws;
    float* p     = ws + P;
    float* a     = ws + 2*P;
    float* b     = ws + 3*P;

    k1_guide_minpool<<<BATCH*64, 256, 0, stream>>>(smoky, guide, p);
    k2_ab<<<BATCH*32, 256, 0, stream>>>(guide, p, a, b);
    k3_final<<<BATCH*32, 256, 0, stream>>>(a, b, guide, smoky, rho, out);
}

// Round 3
// 94.083 us; speedup vs baseline: 1.4214x; 1.4214x over previous
//
#include <hip/hip_runtime.h>

#define BATCH 16
#define HH 512
#define WW 512
#define PLANE (HH*WW)

// Compiler memory-order fences for wave-synchronous LDS exchange.
// HW processes a wave's DS ops in order; these stop the compiler from
// reordering ds_write/ds_read across the cross-lane dependency.
#define LDS_WAIT()   asm volatile("s_waitcnt lgkmcnt(0)" ::: "memory")
#define WAVE_FENCE() asm volatile("" ::: "memory")

// ---------------- K1: guide (channel mean) + 15x15 replicate min-pool ----------------
#define T1 64
#define HALO 7
#define LW (T1 + 2*HALO)   // 78

__global__ __launch_bounds__(256) void k1_guide_minpool(
    const float* __restrict__ smoky, float* __restrict__ guide, float* __restrict__ p)
{
    __shared__ float dcp[LW*LW];     // per-pixel channel min, with replicate halo
    __shared__ float vmn[T1*LW];     // vertical 15-min
    int nwg = gridDim.x;             // 1024, divisible by 8
    int wg = (blockIdx.x & 7) * (nwg >> 3) + (blockIdx.x >> 3);  // XCD-chunked swizzle
    int img  = wg >> 6;              // 64 tiles per image
    int tile = wg & 63;
    int y0 = (tile >> 3) * T1;
    int x0 = (tile & 7) * T1;
    int t = threadIdx.x;
    const float* s0 = smoky + (size_t)img * 3 * PLANE;
    float* gpl = guide + (size_t)img * PLANE;
    float* ppl = p     + (size_t)img * PLANE;

    for (int i = t; i < LW*LW; i += 256) {
        int ly = i / LW, lx = i - ly * LW;
        int iy = y0 - HALO + ly, ix = x0 - HALO + lx;
        int cy = min(max(iy, 0), HH-1);
        int cx = min(max(ix, 0), WW-1);
        const float* bp = s0 + cy * WW + cx;
        float c0 = bp[0], c1 = bp[PLANE], c2 = bp[2*PLANE];
        dcp[i] = fminf(fminf(c0, c1), c2);
        if (ly >= HALO && ly < HALO+T1 && lx >= HALO && lx < HALO+T1)
            gpl[iy * WW + ix] = (c0 + c1 + c2) * (1.0f/3.0f);
    }
    __syncthreads();
    for (int i = t; i < T1*LW; i += 256) {
        int r = i / LW, c = i - r * LW;
        float m = dcp[r*LW + c];
        #pragma unroll
        for (int d = 1; d < 15; ++d) m = fminf(m, dcp[(r+d)*LW + c]);
        vmn[i] = m;
    }
    __syncthreads();
    for (int i = t; i < T1*T1; i += 256) {
        int r = i >> 6, c = i & 63;
        float m = vmn[r*LW + c];
        #pragma unroll
        for (int d = 1; d < 15; ++d) m = fminf(m, vmn[r*LW + c + d]);
        ppl[(y0+r)*WW + x0 + c] = m;
    }
}

// ---------------- K2: wave-autonomous fused box sums (I, I^2, p, I*p) -> a, b ----------------
#define RS2 16

__global__ __launch_bounds__(256) void k2_ab(
    const float* __restrict__ guide, const float* __restrict__ p,
    float* __restrict__ aO, float* __restrict__ bO)
{
    __shared__ float ls[4][4][80];   // [wave][quantity][slot]
    int nwg = gridDim.x;             // 1024
    int wg = (blockIdx.x & 7) * (nwg >> 3) + (blockIdx.x >> 3);
    int w = threadIdx.x >> 6, l = threadIdx.x & 63;
    int gw = wg * 4 + w;             // 0..4095
    int img   = gw >> 8;             // 256 waves per image
    int cg    = (gw >> 5) & 7;
    int strip = gw & 31;
    int y0 = strip * RS2;
    int c0 = cg * 64;
    const float* gP = guide + (size_t)img * PLANE;
    const float* pP = p     + (size_t)img * PLANE;
    float* aPl = aO + (size_t)img * PLANE;
    float* bPl = bO + (size_t)img * PLANE;

    // LDS slot s <-> global column c0-7+s
    int col0 = c0 - 7 + l;      // slot l
    int col1 = c0 + 57 + l;     // slot 64+l (lanes 0..13)
    bool v0 = (col0 >= 0);
    bool v1 = (l < 14) && (col1 < WW);

    float sI0=0,sII0=0,sP0=0,sIp0=0;
    float sI1=0,sII1=0,sP1=0,sIp1=0;

    auto loadrow = [&](int y, float& I0, float& Q0, float& I1, float& Q1) {
        I0 = 0.f; Q0 = 0.f; I1 = 0.f; Q1 = 0.f;
        if ((unsigned)y < (unsigned)HH) {
            const float* gr = gP + (size_t)y * WW;
            const float* pr = pP + (size_t)y * WW;
            if (v0) { I0 = gr[col0]; Q0 = pr[col0]; }
            if (v1) { I1 = gr[col1]; Q1 = pr[col1]; }
        }
    };

    // warm-up: window(y0-1) = rows y0-8 .. y0+6 (15 rows, zero outside)
    for (int r = y0 - 8; r <= y0 + 6; ++r) {
        float I0,Q0,I1,Q1; loadrow(r, I0,Q0,I1,Q1);
        sI0+=I0; sII0+=I0*I0; sP0+=Q0; sIp0+=I0*Q0;
        sI1+=I1; sII1+=I1*I1; sP1+=Q1; sIp1+=I1*Q1;
    }
    float aI0,aQ0,aI1,aQ1, bI0,bQ0,bI1,bQ1;
    loadrow(y0 + 7, aI0,aQ0,aI1,aQ1);   // to add at iter y0
    loadrow(y0 - 8, bI0,bQ0,bI1,bQ1);   // to subtract at iter y0

    float* L = &ls[w][0][0];
    const float inv225 = 1.0f/225.0f;
    for (int y = y0; y < y0 + RS2; ++y) {
        // window(y) = window(y-1) + row(y+7) - row(y-8)
        sI0 += aI0 - bI0;  sII0 += aI0*aI0 - bI0*bI0;
        sP0 += aQ0 - bQ0;  sIp0 += aI0*aQ0 - bI0*bQ0;
        sI1 += aI1 - bI1;  sII1 += aI1*aI1 - bI1*bI1;
        sP1 += aQ1 - bQ1;  sIp1 += aI1*aQ1 - bI1*bQ1;
        // prefetch next iteration's rows (in flight during LDS phase)
        loadrow(y + 8, aI0,aQ0,aI1,aQ1);
        loadrow(y - 7, bI0,bQ0,bI1,bQ1);
        // wave-private LDS exchange (fenced wave-synchronous pattern)
        L[l] = sI0; L[80+l] = sII0; L[160+l] = sP0; L[240+l] = sIp0;
        if (l < 14) { L[64+l] = sI1; L[144+l] = sII1; L[224+l] = sP1; L[304+l] = sIp1; }
        LDS_WAIT();
        float SI=0,SII=0,SP=0,SIp=0;
        #pragma unroll
        for (int d = 0; d < 15; ++d) {
            SI  += L[l+d];
            SII += L[80+l+d];
            SP  += L[160+l+d];
            SIp += L[240+l+d];
        }
        WAVE_FENCE();   // keep next iter's ds_writes below this iter's ds_reads
        float mI = SI*inv225, mP = SP*inv225;
        float va = (SIp*inv225 - mI*mP) / (SII*inv225 - mI*mI + 1e-3f);
        size_t off = (size_t)y*WW + c0 + l;
        aPl[off] = va;
        bPl[off] = mP - va*mI;
    }
}

// ---------------- K3: wave-autonomous box sums of a,b + guided output + combine ----------------
__global__ __launch_bounds__(256) void k3_final(
    const float* __restrict__ aI, const float* __restrict__ bI,
    const float* __restrict__ guide, const float* __restrict__ smoky,
    const float* __restrict__ rho, float* __restrict__ out)
{
    __shared__ float ls[4][2][80];
    int nwg = gridDim.x;             // 1024
    int wg = (blockIdx.x & 7) * (nwg >> 3) + (blockIdx.x >> 3);
    int w = threadIdx.x >> 6, l = threadIdx.x & 63;
    int gw = wg * 4 + w;
    int img   = gw >> 8;
    int cg    = (gw >> 5) & 7;
    int strip = gw & 31;
    int y0 = strip * RS2;
    int c0 = cg * 64;
    const float* aP = aI + (size_t)img * PLANE;
    const float* bP = bI + (size_t)img * PLANE;
    const float* gP = guide + (size_t)img * PLANE;
    const float* sP = smoky + (size_t)img * 3 * PLANE;
    const float* rP = rho   + (size_t)img * 3 * PLANE;
    float* oP = out + (size_t)img * 3 * PLANE;

    int col0 = c0 - 7 + l;
    int col1 = c0 + 57 + l;
    bool v0 = (col0 >= 0);
    bool v1 = (l < 14) && (col1 < WW);

    float sa0=0, sb0=0, sa1=0, sb1=0;

    auto loadrow = [&](int y, float& A0, float& B0, float& A1, float& B1) {
        A0 = 0.f; B0 = 0.f; A1 = 0.f; B1 = 0.f;
        if ((unsigned)y < (unsigned)HH) {
            const float* ar = aP + (size_t)y * WW;
            const float* br = bP + (size_t)y * WW;
            if (v0) { A0 = ar[col0]; B0 = br[col0]; }
            if (v1) { A1 = ar[col1]; B1 = br[col1]; }
        }
    };

    for (int r = y0 - 8; r <= y0 + 6; ++r) {
        float A0,B0,A1,B1; loadrow(r, A0,B0,A1,B1);
        sa0+=A0; sb0+=B0; sa1+=A1; sb1+=B1;
    }
    float aa0,ab0,aa1,ab1, ba0,bb0,ba1,bb1;
    loadrow(y0 + 7, aa0,ab0,aa1,ab1);
    loadrow(y0 - 8, ba0,bb0,ba1,bb1);

    // prefetched emit operands (guide/smoky/rho at current row)
    float eg, es0,es1,es2, er0,er1,er2;
    int yend = y0 + RS2;
    auto loademit = [&](int y) {
        if (y < yend) {
            size_t off = (size_t)y*WW + c0 + l;
            eg  = gP[off];
            es0 = sP[off]; es1 = sP[off+PLANE]; es2 = sP[off+2*PLANE];
            er0 = rP[off]; er1 = rP[off+PLANE]; er2 = rP[off+2*PLANE];
        }
    };
    loademit(y0);

    float* L = &ls[w][0][0];
    const float inv225 = 1.0f/225.0f;
    const float inv11  = 1.0f/1.1f;
    for (int y = y0; y < yend; ++y) {
        sa0 += aa0 - ba0;  sb0 += ab0 - bb0;
        sa1 += aa1 - ba1;  sb1 += ab1 - bb1;
        // consume current emit operands into locals
        float g = eg, s0 = es0, s1 = es1, s2 = es2, r0 = er0, r1 = er1, r2 = er2;
        // prefetch next iteration
        loadrow(y + 8, aa0,ab0,aa1,ab1);
        loadrow(y - 7, ba0,bb0,ba1,bb1);
        loademit(y + 1);
        // wave-private LDS exchange (fenced wave-synchronous pattern)
        L[l] = sa0; L[80+l] = sb0;
        if (l < 14) { L[64+l] = sa1; L[144+l] = sb1; }
        LDS_WAIT();
        float SA=0, SB=0;
        #pragma unroll
        for (int d = 0; d < 15; ++d) { SA += L[l+d]; SB += L[80+l+d]; }
        WAVE_FENCE();
        float dcr = SA*inv225*g + SB*inv225;
        float f = (0.1f + dcr) * inv11;
        size_t off = (size_t)y*WW + c0 + l;
        oP[off]          = s0 - f*(1.0f - r0);
        oP[off+PLANE]    = s1 - f*(1.0f - r1);
        oP[off+2*PLANE]  = s2 - f*(1.0f - r2);
    }
}

extern "C" void kernel_launch(void* const* d_in, const int* in_sizes, int n_in,
                              void* d_out, int out_size, void* d_ws, size_t ws_size,
                              hipStream_t stream) {
    const float* smoky = (const float*)d_in[0];
    const float* rho   = (const float*)d_in[1];
    float* out = (float*)d_out;
    float* ws  = (float*)d_ws;
    const size_t P = (size_t)BATCH * PLANE;
    float* guide = ws;
    float* p     = ws + P;
    float* a     = ws + 2*P;
    float* b     = ws + 3*P;

    k1_guide_minpool<<<BATCH*64, 256, 0, stream>>>(smoky, guide, p);
    k2_ab<<<BATCH*64, 256, 0, stream>>>(guide, p, a, b);
    k3_final<<<BATCH*64, 256, 0, stream>>>(a, b, guide, smoky, rho, out);
}